// Round 1
// baseline (121.846 us; speedup 1.0000x reference)
//
#include <hip/hip_runtime.h>
#include <hip/hip_bf16.h>
#include <stdint.h>

#define M_DIM 2048
#define N_DIM 4096
#define K_DIM 4096

#define BM 128
#define BN 128
#define BK 64

typedef short short8 __attribute__((ext_vector_type(8)));
typedef float f32x4 __attribute__((ext_vector_type(4)));

typedef __attribute__((address_space(1))) unsigned int gu32;
typedef __attribute__((address_space(3))) unsigned int lu32;

// async global->LDS, 16B per lane; LDS dest = wave-uniform base + lane*16
__device__ static inline void async_copy16(const unsigned short* g, unsigned short* l) {
  __builtin_amdgcn_global_load_lds((gu32*)g, (lu32*)l, 16, 0, 0);
}

// f32 -> bf16 round-to-nearest-even (no NaN in this problem)
__device__ static inline unsigned short f32_to_bf16(float f) {
  union { float f; unsigned int u; } v; v.f = f;
  unsigned int u = v.u;
  u += 0x7FFFu + ((u >> 16) & 1u);
  return (unsigned short)(u >> 16);
}

// ---- x: f32 [M][K] -> bf16 [M][K] ----
__global__ void cvt_x_kernel(const float* __restrict__ in, unsigned short* __restrict__ out) {
  size_t i = ((size_t)blockIdx.x * blockDim.x + threadIdx.x) * 8;
  f32x4 a = *(const f32x4*)(in + i);
  f32x4 b = *(const f32x4*)(in + i + 4);
  short8 o;
  o[0] = (short)f32_to_bf16(a[0]); o[1] = (short)f32_to_bf16(a[1]);
  o[2] = (short)f32_to_bf16(a[2]); o[3] = (short)f32_to_bf16(a[3]);
  o[4] = (short)f32_to_bf16(b[0]); o[5] = (short)f32_to_bf16(b[1]);
  o[6] = (short)f32_to_bf16(b[2]); o[7] = (short)f32_to_bf16(b[3]);
  *(short8*)(out + i) = o;
}

// ---- w: f32 [K][N] -> bf16 Bt [N][K] (64x64 LDS tiles, both sides coalesced) ----
__global__ void transpose_cvt_w_kernel(const float* __restrict__ w, unsigned short* __restrict__ wt) {
  __shared__ unsigned short tile[64][64 + 8];
  int bn = blockIdx.x * 64;  // n block
  int bk = blockIdx.y * 64;  // k block
  int t = threadIdx.x;       // 256 threads
  int c4 = (t & 15) * 4;     // col (n) offset
  int r0 = t >> 4;           // 0..15
#pragma unroll
  for (int p = 0; p < 4; ++p) {
    int r = r0 + p * 16;  // k row in tile
    f32x4 v = *(const f32x4*)(w + (size_t)(bk + r) * N_DIM + bn + c4);
    tile[c4 + 0][r] = f32_to_bf16(v[0]);
    tile[c4 + 1][r] = f32_to_bf16(v[1]);
    tile[c4 + 2][r] = f32_to_bf16(v[2]);
    tile[c4 + 3][r] = f32_to_bf16(v[3]);
  }
  __syncthreads();
  int orow = t >> 2;        // n row 0..63
  int oc = (t & 3) * 16;    // k col base
  short8 lo, hi;
#pragma unroll
  for (int j = 0; j < 8; ++j) {
    lo[j] = (short)tile[orow][oc + j];
    hi[j] = (short)tile[orow][oc + 8 + j];
  }
  unsigned short* op = wt + (size_t)(bn + orow) * K_DIM + bk + oc;
  *(short8*)(op) = lo;
  *(short8*)(op + 8) = hi;
}

// ---- GEMM: C[M][N] = relu(fxp(A@B) + fxp(b)) ----
// USE_WS=1: A bf16 [M][K], Bt bf16 [N][K] from workspace, global_load_lds staging.
// USE_WS=0: stage+convert f32 x [M][K] / w [K][N] via registers (fallback).
template <int USE_WS>
__global__ __launch_bounds__(256, 2) void gemm_kernel(
    const unsigned short* __restrict__ A, const unsigned short* __restrict__ Bt,
    const float* __restrict__ Xf, const float* __restrict__ Wf,
    const float* __restrict__ bias, float* __restrict__ C) {
  __shared__ unsigned short As[BM][BK];
  __shared__ unsigned short Bs[BN][BK];

  int tid = threadIdx.x;
  int lane = tid & 63;
  int wid = tid >> 6;
  int wr = wid >> 1, wc = wid & 1;
  int r0 = blockIdx.y * BM;
  int c0 = blockIdx.x * BN;

  f32x4 acc[4][4] = {};

  for (int kt = 0; kt < K_DIM / BK; ++kt) {
    __syncthreads();  // previous compute done before overwriting LDS
    if constexpr (USE_WS) {
      // 16 chunks of 1KB per operand tile; wave w stages chunks 4w..4w+3
      int rowi = (lane >> 3);        // 0..7 within chunk
      int colb = (lane & 7) * 8;     // bf16 col
#pragma unroll
      for (int c = 0; c < 4; ++c) {
        int chunk = wid * 4 + c;
        int row = chunk * 8 + rowi;
        async_copy16(A + (size_t)(r0 + row) * K_DIM + kt * BK + colb,
                     &As[0][0] + chunk * 512);
        async_copy16(Bt + (size_t)(c0 + row) * K_DIM + kt * BK + colb,
                     &Bs[0][0] + chunk * 512);
      }
    } else {
      // A: 128 rows x 64 cols, 2 threads/row
      int ar = tid >> 1;
      int ac = (tid & 1) * 32;
      const float* xp = Xf + (size_t)(r0 + ar) * K_DIM + kt * BK + ac;
#pragma unroll
      for (int j = 0; j < 8; ++j) {
        f32x4 v = *(const f32x4*)(xp + j * 4);
        As[ar][ac + j * 4 + 0] = f32_to_bf16(v[0]);
        As[ar][ac + j * 4 + 1] = f32_to_bf16(v[1]);
        As[ar][ac + j * 4 + 2] = f32_to_bf16(v[2]);
        As[ar][ac + j * 4 + 3] = f32_to_bf16(v[3]);
      }
      // B: w[k][n] -> Bs[n][k]; 64 k-rows, 4 threads/k-row
      int bk_ = tid >> 2;
      int bc = (tid & 3) * 32;
      const float* wp = Wf + (size_t)(kt * BK + bk_) * N_DIM + c0 + bc;
#pragma unroll
      for (int j = 0; j < 8; ++j) {
        f32x4 v = *(const f32x4*)(wp + j * 4);
        Bs[bc + j * 4 + 0][bk_] = f32_to_bf16(v[0]);
        Bs[bc + j * 4 + 1][bk_] = f32_to_bf16(v[1]);
        Bs[bc + j * 4 + 2][bk_] = f32_to_bf16(v[2]);
        Bs[bc + j * 4 + 3][bk_] = f32_to_bf16(v[3]);
      }
    }
    __syncthreads();  // staging visible (compiler drains vmcnt before barrier)

#pragma unroll
    for (int ks = 0; ks < 2; ++ks) {
      int co = ks * 32 + (lane >> 4) * 8;  // same (g,e)->k map for A and B => permutation-safe
      int rA = wr * 64 + (lane & 15);
      int rB = wc * 64 + (lane & 15);
      short8 a[4], b[4];
#pragma unroll
      for (int m = 0; m < 4; ++m) a[m] = *(const short8*)&As[rA + m * 16][co];
#pragma unroll
      for (int n = 0; n < 4; ++n) b[n] = *(const short8*)&Bs[rB + n * 16][co];
#pragma unroll
      for (int m = 0; m < 4; ++m)
#pragma unroll
        for (int n = 0; n < 4; ++n)
          acc[m][n] = __builtin_amdgcn_mfma_f32_16x16x32_bf16(a[m], b[n], acc[m][n], 0, 0, 0);
    }
  }

  // epilogue: fxp(y) + fxp(b), relu (final fxp is exact identity on-grid)
  const float S = 65536.0f, IS = 1.0f / 65536.0f;
  int lr = (lane >> 4) * 4;  // C/D: row=(lane>>4)*4+reg, col=lane&15 (m89-verified)
  int lc = lane & 15;
#pragma unroll
  for (int n = 0; n < 4; ++n) {
    int gcol = c0 + wc * 64 + n * 16 + lc;
    float bq = rintf(bias[gcol] * S) * IS;
#pragma unroll
    for (int m = 0; m < 4; ++m) {
      int grow = r0 + wr * 64 + m * 16 + lr;
      float* outp = C + (size_t)grow * N_DIM + gcol;
#pragma unroll
      for (int r = 0; r < 4; ++r) {
        float t = rintf(acc[m][n][r] * S) * IS + bq;
        t = t > 0.0f ? t : 0.0f;
        outp[(size_t)r * N_DIM] = t;
      }
    }
  }
}

extern "C" void kernel_launch(void* const* d_in, const int* in_sizes, int n_in,
                              void* d_out, int out_size, void* d_ws, size_t ws_size,
                              hipStream_t stream) {
  const float* x = (const float*)d_in[0];
  const float* w = (const float*)d_in[1];
  const float* b = (const float*)d_in[2];
  float* out = (float*)d_out;

  size_t needA = (size_t)M_DIM * K_DIM * sizeof(unsigned short);
  size_t needB = (size_t)K_DIM * N_DIM * sizeof(unsigned short);
  dim3 ggrid(N_DIM / BN, M_DIM / BM);

  if (ws_size >= needA + needB) {
    unsigned short* Abf = (unsigned short*)d_ws;
    unsigned short* Btbf = (unsigned short*)((char*)d_ws + needA);
    cvt_x_kernel<<<(M_DIM * (size_t)K_DIM / 8 + 255) / 256, 256, 0, stream>>>(x, Abf);
    transpose_cvt_w_kernel<<<dim3(N_DIM / 64, K_DIM / 64), 256, 0, stream>>>(w, Btbf);
    gemm_kernel<1><<<ggrid, 256, 0, stream>>>(Abf, Btbf, nullptr, nullptr, b, out);
  } else {
    gemm_kernel<0><<<ggrid, 256, 0, stream>>>(nullptr, nullptr, x, w, b, out);
  }
}

// Round 3
// 94.327 us; speedup vs baseline: 1.2917x; 1.2917x over previous
//
#include <hip/hip_runtime.h>
#include <hip/hip_bf16.h>
#include <stdint.h>

#define M_DIM 2048
#define N_DIM 4096
#define K_DIM 4096

#define NT 64  // K tiles of 64

typedef short short8 __attribute__((ext_vector_type(8)));
typedef float f32x4 __attribute__((ext_vector_type(4)));

typedef __attribute__((address_space(1))) unsigned int gu32;
typedef __attribute__((address_space(3))) unsigned int lu32;

// f32 -> bf16 round-to-nearest-even
__device__ static inline unsigned short f32_to_bf16(float f) {
  union { float f; unsigned int u; } v; v.f = f;
  unsigned int u = v.u;
  u += 0x7FFFu + ((u >> 16) & 1u);
  return (unsigned short)(u >> 16);
}

// ---- x: f32 [M][K] -> bf16 [M][K] ----
__global__ void cvt_x_kernel(const float* __restrict__ in, unsigned short* __restrict__ out) {
  size_t i = ((size_t)blockIdx.x * blockDim.x + threadIdx.x) * 8;
  f32x4 a = *(const f32x4*)(in + i);
  f32x4 b = *(const f32x4*)(in + i + 4);
  short8 o;
  o[0] = (short)f32_to_bf16(a[0]); o[1] = (short)f32_to_bf16(a[1]);
  o[2] = (short)f32_to_bf16(a[2]); o[3] = (short)f32_to_bf16(a[3]);
  o[4] = (short)f32_to_bf16(b[0]); o[5] = (short)f32_to_bf16(b[1]);
  o[6] = (short)f32_to_bf16(b[2]); o[7] = (short)f32_to_bf16(b[3]);
  *(short8*)(out + i) = o;
}

// ---- w: f32 [K][N] -> bf16 Bt [N][K] ----
__global__ void transpose_cvt_w_kernel(const float* __restrict__ w, unsigned short* __restrict__ wt) {
  __shared__ unsigned short tile[64][64 + 8];
  int bn = blockIdx.x * 64;
  int bk = blockIdx.y * 64;
  int t = threadIdx.x;
  int c4 = (t & 15) * 4;
  int r0 = t >> 4;
#pragma unroll
  for (int p = 0; p < 4; ++p) {
    int r = r0 + p * 16;
    f32x4 v = *(const f32x4*)(w + (size_t)(bk + r) * N_DIM + bn + c4);
    tile[c4 + 0][r] = f32_to_bf16(v[0]);
    tile[c4 + 1][r] = f32_to_bf16(v[1]);
    tile[c4 + 2][r] = f32_to_bf16(v[2]);
    tile[c4 + 3][r] = f32_to_bf16(v[3]);
  }
  __syncthreads();
  int orow = t >> 2;
  int oc = (t & 3) * 16;
  short8 lo, hi;
#pragma unroll
  for (int j = 0; j < 8; ++j) {
    lo[j] = (short)tile[orow][oc + j];
    hi[j] = (short)tile[orow][oc + 8 + j];
  }
  unsigned short* op = wt + (size_t)(bn + orow) * K_DIM + bk + oc;
  *(short8*)(op) = lo;
  *(short8*)(op + 8) = hi;
}

// ===================== phase-interleaved GEMM =====================
// BM=128, BN=256, BK=64. 512 threads = 8 waves (2M x 4N), wave tile 64x64.
// LDS: 3 sides x (A 16KB + B 32KB) = 144KB. Tile t lives in side t%3.
// While computing tile t, stage tile t+2 into side (t+2)%3 == (t-1)%3
// (last read at t-1's end barrier => WAR-safe). Counted vmcnt(6) per tile.
// CRITICAL sync invariant (round-2 bug): vmcnt is PER-WAVE; a wave reads LDS
// staged by OTHER waves, so every wave's vmcnt covering tile t must be
// followed by an s_barrier BEFORE any wave ds_reads tile t's buffer.
// XOR swizzle: LDS 16B-slot sigma = chunk ^ (row&7); writes realized by
// pre-swizzled per-lane GLOBAL address + linear LDS dest (global_load_lds),
// reads apply the same XOR => 8 lanes per 4-bank group = conflict-free floor.

__global__ __launch_bounds__(512) void gemm8_kernel(
    const unsigned short* __restrict__ A, const unsigned short* __restrict__ Bt,
    const float* __restrict__ bias, float* __restrict__ C) {
  __shared__ unsigned short sm16[3 * 24576];  // 147456 B
  char* smem = (char*)&sm16[0];

  const int tid = threadIdx.x;
  const int lane = tid & 63;
  const int w = tid >> 6;
  const int wm = w >> 2, wn = w & 3;

  // 8x4 region remap for L2 locality (bijective over 256 blocks)
  const int id = blockIdx.x;
  const int x = id & 7, j = id >> 3;
  const int by = ((x >> 2) << 3) + (j >> 2);
  const int bx = ((x & 3) << 2) + (j & 3);
  const int r0 = by * 128, c0 = bx * 256;

  // ---- staging precompute ----
  const int l8 = lane >> 3, l7 = lane & 7;
  const int chunkE = ((l7 ^ (l8 & 7)) << 3);  // pre-swizzled k-chunk (bf16 elems)
  const unsigned short* Ag = A + (size_t)(r0 + w * 16 + l8) * K_DIM + chunkE;
  const unsigned short* Bg = Bt + (size_t)(c0 + w * 32 + l8) * K_DIM + chunkE;
  const int aL0 = w * 2048;          // byte offset of wave's A chunk within side
  const int bL0 = 16384 + w * 4096;  // byte offset of wave's B chunk within side

#define GL(gp, ldsoff) __builtin_amdgcn_global_load_lds((gu32*)(gp), (lu32*)(smem + (ldsoff)), 16, 0, 0)
#define STAGE_P0(t, sb)                                       \
  do {                                                        \
    GL(Ag + (size_t)(t) * 64, (sb) + aL0);                    \
    GL(Ag + (size_t)(t) * 64 + 8 * (size_t)K_DIM, (sb) + aL0 + 1024); \
    GL(Bg + (size_t)(t) * 64, (sb) + bL0);                    \
  } while (0)
#define STAGE_P1(t, sb)                                       \
  do {                                                        \
    GL(Bg + (size_t)(t) * 64 + 8 * (size_t)K_DIM, (sb) + bL0 + 1024);  \
    GL(Bg + (size_t)(t) * 64 + 16 * (size_t)K_DIM, (sb) + bL0 + 2048); \
    GL(Bg + (size_t)(t) * 64 + 24 * (size_t)K_DIM, (sb) + bL0 + 3072); \
  } while (0)

  // ---- fragment-read precompute (ushort units within side) ----
  const int l15 = lane & 15, hi = lane >> 4;
  const int aR = (wm * 64 + l15) * 64;         // A row base
  const int bR = 8192 + (wn * 64 + l15) * 64;  // B row base (B region at 16KB)
  const int slot0 = ((hi ^ l7) << 3);          // ks=0: chunk hi at slot hi^(row&7)
  const int slot1 = (((4 + hi) ^ l7) << 3);    // ks=1: chunk 4+hi

  f32x4 acc[4][4] = {};

  // prologue: stage tiles 0 and 1
  STAGE_P0(0, 0); STAGE_P1(0, 0);
  STAGE_P0(1, 49152); STAGE_P1(1, 49152);

  int cs = 0;  // side of tile t
  for (int t = 0; t < NT; ++t) {
    const int sE = cs * 24576;                         // compute side (ushorts)
    const int stB = (cs == 0 ? 2 : cs - 1) * 49152;    // stage side == (t+2)%3 (bytes)
    const bool doStage = (t + 2) < NT;

    // wave-local completion of tile t's loads...
    if (t < NT - 1) asm volatile("s_waitcnt vmcnt(6)" ::: "memory");
    else            asm volatile("s_waitcnt vmcnt(0)" ::: "memory");
    // ...published to ALL waves before anyone ds_reads tile t (round-2 fix)
    asm volatile("s_barrier" ::: "memory");

    // ================= phase 0 (ks = 0) =================
    {
      short8 a[4], b[4];
#pragma unroll
      for (int m = 0; m < 4; ++m) a[m] = *(const short8*)(sm16 + sE + aR + m * 1024 + slot0);
#pragma unroll
      for (int n = 0; n < 4; ++n) b[n] = *(const short8*)(sm16 + sE + bR + n * 1024 + slot0);
      if (doStage) STAGE_P0(t + 2, stB);
      asm volatile("s_barrier" ::: "memory");
      __builtin_amdgcn_s_setprio(1);
#pragma unroll
      for (int m = 0; m < 4; ++m)
#pragma unroll
        for (int n = 0; n < 4; ++n)
          acc[m][n] = __builtin_amdgcn_mfma_f32_16x16x32_bf16(a[m], b[n], acc[m][n], 0, 0, 0);
      __builtin_amdgcn_s_setprio(0);
      asm volatile("s_barrier" ::: "memory");
    }
    // ================= phase 1 (ks = 1) =================
    {
      short8 a[4], b[4];
#pragma unroll
      for (int m = 0; m < 4; ++m) a[m] = *(const short8*)(sm16 + sE + aR + m * 1024 + slot1);
#pragma unroll
      for (int n = 0; n < 4; ++n) b[n] = *(const short8*)(sm16 + sE + bR + n * 1024 + slot1);
      if (doStage) STAGE_P1(t + 2, stB);
      asm volatile("s_barrier" ::: "memory");
      __builtin_amdgcn_s_setprio(1);
#pragma unroll
      for (int m = 0; m < 4; ++m)
#pragma unroll
        for (int n = 0; n < 4; ++n)
          acc[m][n] = __builtin_amdgcn_mfma_f32_16x16x32_bf16(a[m], b[n], acc[m][n], 0, 0, 0);
      __builtin_amdgcn_s_setprio(0);
      asm volatile("s_barrier" ::: "memory");
    }
    cs = (cs == 2) ? 0 : cs + 1;
  }

  // ---- epilogue: fxp(y) + fxp(b), relu ----
  const float S = 65536.0f, IS = 1.0f / 65536.0f;
  const int lr = hi * 4;  // C/D: row=(lane>>4)*4+reg, col=lane&15
#pragma unroll
  for (int n = 0; n < 4; ++n) {
    int gcol = c0 + wn * 64 + n * 16 + l15;
    float bq = rintf(bias[gcol] * S) * IS;
#pragma unroll
    for (int m = 0; m < 4; ++m) {
      int grow = r0 + wm * 64 + m * 16 + lr;
      float* outp = C + (size_t)grow * N_DIM + gcol;
#pragma unroll
      for (int r = 0; r < 4; ++r) {
        float t = rintf(acc[m][n][r] * S) * IS + bq;
        t = t > 0.0f ? t : 0.0f;
        outp[(size_t)r * N_DIM] = t;
      }
    }
  }
#undef GL
#undef STAGE_P0
#undef STAGE_P1
}

// ---- fallback (small workspace): round-1 reg-staged kernel ----
__global__ __launch_bounds__(256, 2) void gemm_fb_kernel(
    const float* __restrict__ Xf, const float* __restrict__ Wf,
    const float* __restrict__ bias, float* __restrict__ C) {
  __shared__ unsigned short As[128][64];
  __shared__ unsigned short Bs[128][64];
  int tid = threadIdx.x;
  int lane = tid & 63;
  int wid = tid >> 6;
  int wr = wid >> 1, wc = wid & 1;
  int r0 = blockIdx.y * 128;
  int c0 = blockIdx.x * 128;
  f32x4 acc[4][4] = {};
  for (int kt = 0; kt < K_DIM / 64; ++kt) {
    __syncthreads();
    int ar = tid >> 1;
    int ac = (tid & 1) * 32;
    const float* xp = Xf + (size_t)(r0 + ar) * K_DIM + kt * 64 + ac;
#pragma unroll
    for (int jj = 0; jj < 8; ++jj) {
      f32x4 v = *(const f32x4*)(xp + jj * 4);
      As[ar][ac + jj * 4 + 0] = f32_to_bf16(v[0]);
      As[ar][ac + jj * 4 + 1] = f32_to_bf16(v[1]);
      As[ar][ac + jj * 4 + 2] = f32_to_bf16(v[2]);
      As[ar][ac + jj * 4 + 3] = f32_to_bf16(v[3]);
    }
    int bk_ = tid >> 2;
    int bc = (tid & 3) * 32;
    const float* wp = Wf + (size_t)(kt * 64 + bk_) * N_DIM + c0 + bc;
#pragma unroll
    for (int jj = 0; jj < 8; ++jj) {
      f32x4 v = *(const f32x4*)(wp + jj * 4);
      Bs[bc + jj * 4 + 0][bk_] = f32_to_bf16(v[0]);
      Bs[bc + jj * 4 + 1][bk_] = f32_to_bf16(v[1]);
      Bs[bc + jj * 4 + 2][bk_] = f32_to_bf16(v[2]);
      Bs[bc + jj * 4 + 3][bk_] = f32_to_bf16(v[3]);
    }
    __syncthreads();
#pragma unroll
    for (int ks = 0; ks < 2; ++ks) {
      int co = ks * 32 + (lane >> 4) * 8;
      int rA = wr * 64 + (lane & 15);
      int rB = wc * 64 + (lane & 15);
      short8 a[4], b[4];
#pragma unroll
      for (int m = 0; m < 4; ++m) a[m] = *(const short8*)&As[rA + m * 16][co];
#pragma unroll
      for (int n = 0; n < 4; ++n) b[n] = *(const short8*)&Bs[rB + n * 16][co];
#pragma unroll
      for (int m = 0; m < 4; ++m)
#pragma unroll
        for (int n = 0; n < 4; ++n)
          acc[m][n] = __builtin_amdgcn_mfma_f32_16x16x32_bf16(a[m], b[n], acc[m][n], 0, 0, 0);
    }
  }
  const float S = 65536.0f, IS = 1.0f / 65536.0f;
  int lr = (lane >> 4) * 4;
  int lc = lane & 15;
#pragma unroll
  for (int n = 0; n < 4; ++n) {
    int gcol = c0 + wc * 64 + n * 16 + lc;
    float bq = rintf(bias[gcol] * S) * IS;
#pragma unroll
    for (int m = 0; m < 4; ++m) {
      int grow = r0 + wr * 64 + m * 16 + lr;
      float* outp = C + (size_t)grow * N_DIM + gcol;
#pragma unroll
      for (int r = 0; r < 4; ++r) {
        float t = rintf(acc[m][n][r] * S) * IS + bq;
        t = t > 0.0f ? t : 0.0f;
        outp[(size_t)r * N_DIM] = t;
      }
    }
  }
}

extern "C" void kernel_launch(void* const* d_in, const int* in_sizes, int n_in,
                              void* d_out, int out_size, void* d_ws, size_t ws_size,
                              hipStream_t stream) {
  const float* x = (const float*)d_in[0];
  const float* w = (const float*)d_in[1];
  const float* b = (const float*)d_in[2];
  float* out = (float*)d_out;

  size_t needA = (size_t)M_DIM * K_DIM * sizeof(unsigned short);
  size_t needB = (size_t)K_DIM * N_DIM * sizeof(unsigned short);

  if (ws_size >= needA + needB) {
    unsigned short* Abf = (unsigned short*)d_ws;
    unsigned short* Btbf = (unsigned short*)((char*)d_ws + needA);
    cvt_x_kernel<<<(M_DIM * (size_t)K_DIM / 8 + 255) / 256, 256, 0, stream>>>(x, Abf);
    transpose_cvt_w_kernel<<<dim3(N_DIM / 64, K_DIM / 64), 256, 0, stream>>>(w, Btbf);
    gemm8_kernel<<<256, 512, 0, stream>>>(Abf, Btbf, b, out);
  } else {
    gemm_fb_kernel<<<dim3(N_DIM / 128, M_DIM / 128), 256, 0, stream>>>(x, w, b, out);
  }
}

// Round 4
// 90.885 us; speedup vs baseline: 1.3407x; 1.0379x over previous
//
#include <hip/hip_runtime.h>
#include <hip/hip_bf16.h>
#include <stdint.h>

#define M_DIM 2048
#define N_DIM 4096
#define K_DIM 4096

#define NT 64  // K tiles of 64

typedef short short8 __attribute__((ext_vector_type(8)));
typedef float f32x4 __attribute__((ext_vector_type(4)));

typedef __attribute__((address_space(1))) unsigned int gu32;
typedef __attribute__((address_space(3))) unsigned int lu32;

// f32 -> bf16 round-to-nearest-even
__device__ static inline unsigned short f32_to_bf16(float f) {
  union { float f; unsigned int u; } v; v.f = f;
  unsigned int u = v.u;
  u += 0x7FFFu + ((u >> 16) & 1u);
  return (unsigned short)(u >> 16);
}

// ---- x: f32 [M][K] -> bf16 [M][K] ----
__global__ void cvt_x_kernel(const float* __restrict__ in, unsigned short* __restrict__ out) {
  size_t i = ((size_t)blockIdx.x * blockDim.x + threadIdx.x) * 8;
  f32x4 a = *(const f32x4*)(in + i);
  f32x4 b = *(const f32x4*)(in + i + 4);
  short8 o;
  o[0] = (short)f32_to_bf16(a[0]); o[1] = (short)f32_to_bf16(a[1]);
  o[2] = (short)f32_to_bf16(a[2]); o[3] = (short)f32_to_bf16(a[3]);
  o[4] = (short)f32_to_bf16(b[0]); o[5] = (short)f32_to_bf16(b[1]);
  o[6] = (short)f32_to_bf16(b[2]); o[7] = (short)f32_to_bf16(b[3]);
  *(short8*)(out + i) = o;
}

// ---- w: f32 [K][N] -> bf16 Bt [N][K] ----
__global__ void transpose_cvt_w_kernel(const float* __restrict__ w, unsigned short* __restrict__ wt) {
  __shared__ unsigned short tile[64][64 + 8];
  int bn = blockIdx.x * 64;
  int bk = blockIdx.y * 64;
  int t = threadIdx.x;
  int c4 = (t & 15) * 4;
  int r0 = t >> 4;
#pragma unroll
  for (int p = 0; p < 4; ++p) {
    int r = r0 + p * 16;
    f32x4 v = *(const f32x4*)(w + (size_t)(bk + r) * N_DIM + bn + c4);
    tile[c4 + 0][r] = f32_to_bf16(v[0]);
    tile[c4 + 1][r] = f32_to_bf16(v[1]);
    tile[c4 + 2][r] = f32_to_bf16(v[2]);
    tile[c4 + 3][r] = f32_to_bf16(v[3]);
  }
  __syncthreads();
  int orow = t >> 2;
  int oc = (t & 3) * 16;
  short8 lo, hi;
#pragma unroll
  for (int j = 0; j < 8; ++j) {
    lo[j] = (short)tile[orow][oc + j];
    hi[j] = (short)tile[orow][oc + 8 + j];
  }
  unsigned short* op = wt + (size_t)(bn + orow) * K_DIM + bk + oc;
  *(short8*)(op) = lo;
  *(short8*)(op + 8) = hi;
}

// ===================== merged-body GEMM (round 4) =====================
// BM=128, BN=256, BK=64. 512 threads = 8 waves (2M x 4N), wave tile 64x64.
// LDS: 3 sides x 48KB = 144KB. Tile t in side t%3; during body t stage
// tile t+2 into side (t+2)%3 == (t-1)%3.
// ONE barrier per tile: {vmcnt(6) lgkmcnt(0); sched_barrier; s_barrier}
// then merged body {16 ds_read + 6 global_load_lds + 32 MFMA} so the
// compiler overlaps LDS-port time (~1536 cyc/CU/tile) with MFMA-pipe time
// (~1242 cyc/CU/tile) via counted lgkmcnt instead of serializing them
// (round-3: 4 barriers/tile => sum ~2900 cyc/tile, MfmaUtil 35.7%).
// Hazards: RAW covered by vmcnt+barrier at top; WAR (stage into (t-1)%3)
// covered because every wave executes lgkmcnt(0) before the top barrier,
// so all side-(t-1) ds_reads are complete chip-wide; sched_barrier(0)
// prevents hipcc sinking register-only ops past the inline-asm wait.
// XOR swizzle unchanged (slot sigma = chunk ^ (row&7)); bank conflicts = 0.

__global__ __launch_bounds__(512) void gemm8_kernel(
    const unsigned short* __restrict__ A, const unsigned short* __restrict__ Bt,
    const float* __restrict__ bias, float* __restrict__ C) {
  __shared__ unsigned short sm16[3 * 24576];  // 147456 B
  char* smem = (char*)&sm16[0];

  const int tid = threadIdx.x;
  const int lane = tid & 63;
  const int w = tid >> 6;
  const int wm = w >> 2, wn = w & 3;

  // 8x4 region remap for L2 locality (bijective over 256 blocks)
  const int id = blockIdx.x;
  const int x = id & 7, j = id >> 3;
  const int by = ((x >> 2) << 3) + (j >> 2);
  const int bx = ((x & 3) << 2) + (j & 3);
  const int r0 = by * 128, c0 = bx * 256;

  // ---- staging precompute ----
  const int l8 = lane >> 3, l7 = lane & 7;
  const int chunkE = ((l7 ^ (l8 & 7)) << 3);  // pre-swizzled k-chunk (bf16 elems)
  const unsigned short* Ag = A + (size_t)(r0 + w * 16 + l8) * K_DIM + chunkE;
  const unsigned short* Bg = Bt + (size_t)(c0 + w * 32 + l8) * K_DIM + chunkE;
  const int aL0 = w * 2048;          // byte offset of wave's A chunk within side
  const int bL0 = 16384 + w * 4096;  // byte offset of wave's B chunk within side

#define GL(gp, ldsoff) __builtin_amdgcn_global_load_lds((gu32*)(gp), (lu32*)(smem + (ldsoff)), 16, 0, 0)
#define STAGE_ALL(t, sb)                                               \
  do {                                                                 \
    GL(Ag + (size_t)(t) * 64, (sb) + aL0);                             \
    GL(Ag + (size_t)(t) * 64 + 8 * (size_t)K_DIM, (sb) + aL0 + 1024);  \
    GL(Bg + (size_t)(t) * 64, (sb) + bL0);                             \
    GL(Bg + (size_t)(t) * 64 + 8 * (size_t)K_DIM, (sb) + bL0 + 1024);  \
    GL(Bg + (size_t)(t) * 64 + 16 * (size_t)K_DIM, (sb) + bL0 + 2048); \
    GL(Bg + (size_t)(t) * 64 + 24 * (size_t)K_DIM, (sb) + bL0 + 3072); \
  } while (0)

  // ---- fragment-read precompute (ushort units within side) ----
  const int l15 = lane & 15, hi = lane >> 4;
  const int aR = (wm * 64 + l15) * 64;         // A row base
  const int bR = 8192 + (wn * 64 + l15) * 64;  // B row base (B region at 16KB)
  const int slot0 = ((hi ^ l7) << 3);          // ks=0: chunk hi at slot hi^(row&7)
  const int slot1 = (((4 + hi) ^ l7) << 3);    // ks=1: chunk 4+hi

  f32x4 acc[4][4] = {};

  // prologue: stage tiles 0 and 1
  STAGE_ALL(0, 0);
  STAGE_ALL(1, 49152);

  int cs = 0;  // side of tile t
  for (int t = 0; t < NT; ++t) {
    const int sE = cs * 24576;                       // compute side (ushorts)
    const int stB = (cs == 0 ? 2 : cs - 1) * 49152;  // stage side (bytes)
    const bool doStage = (t + 2) < NT;

    // single sync point per tile: my loads for tile t landed (vmcnt),
    // my side-(t-1) ds_reads complete (lgkmcnt), publish to all waves.
    if (t < NT - 1) asm volatile("s_waitcnt vmcnt(6) lgkmcnt(0)" ::: "memory");
    else            asm volatile("s_waitcnt vmcnt(0) lgkmcnt(0)" ::: "memory");
    __builtin_amdgcn_sched_barrier(0);
    asm volatile("s_barrier" ::: "memory");

    // -------- merged body: reads + stage + MFMA, compiler-interleaved ----
    short8 a0[4], b0[4], a1[4], b1[4];
#pragma unroll
    for (int m = 0; m < 4; ++m) a0[m] = *(const short8*)(sm16 + sE + aR + m * 1024 + slot0);
#pragma unroll
    for (int n = 0; n < 4; ++n) b0[n] = *(const short8*)(sm16 + sE + bR + n * 1024 + slot0);
    if (doStage) STAGE_ALL(t + 2, stB);
#pragma unroll
    for (int m = 0; m < 4; ++m) a1[m] = *(const short8*)(sm16 + sE + aR + m * 1024 + slot1);
#pragma unroll
    for (int n = 0; n < 4; ++n) b1[n] = *(const short8*)(sm16 + sE + bR + n * 1024 + slot1);

    __builtin_amdgcn_s_setprio(1);
#pragma unroll
    for (int m = 0; m < 4; ++m)
#pragma unroll
      for (int n = 0; n < 4; ++n)
        acc[m][n] = __builtin_amdgcn_mfma_f32_16x16x32_bf16(a0[m], b0[n], acc[m][n], 0, 0, 0);
#pragma unroll
    for (int m = 0; m < 4; ++m)
#pragma unroll
      for (int n = 0; n < 4; ++n)
        acc[m][n] = __builtin_amdgcn_mfma_f32_16x16x32_bf16(a1[m], b1[n], acc[m][n], 0, 0, 0);
    __builtin_amdgcn_s_setprio(0);

    cs = (cs == 2) ? 0 : cs + 1;
  }

  // ---- epilogue: fxp(y) + fxp(b), relu ----
  const float S = 65536.0f, IS = 1.0f / 65536.0f;
  const int lr = hi * 4;  // C/D: row=(lane>>4)*4+reg, col=lane&15
#pragma unroll
  for (int n = 0; n < 4; ++n) {
    int gcol = c0 + wn * 64 + n * 16 + l15;
    float bq = rintf(bias[gcol] * S) * IS;
#pragma unroll
    for (int m = 0; m < 4; ++m) {
      int grow = r0 + wm * 64 + m * 16 + lr;
      float* outp = C + (size_t)grow * N_DIM + gcol;
#pragma unroll
      for (int r = 0; r < 4; ++r) {
        float t = rintf(acc[m][n][r] * S) * IS + bq;
        t = t > 0.0f ? t : 0.0f;
        outp[(size_t)r * N_DIM] = t;
      }
    }
  }
#undef GL
#undef STAGE_ALL
}

// ---- fallback (small workspace): round-1 reg-staged kernel ----
__global__ __launch_bounds__(256, 2) void gemm_fb_kernel(
    const float* __restrict__ Xf, const float* __restrict__ Wf,
    const float* __restrict__ bias, float* __restrict__ C) {
  __shared__ unsigned short As[128][64];
  __shared__ unsigned short Bs[128][64];
  int tid = threadIdx.x;
  int lane = tid & 63;
  int wid = tid >> 6;
  int wr = wid >> 1, wc = wid & 1;
  int r0 = blockIdx.y * 128;
  int c0 = blockIdx.x * 128;
  f32x4 acc[4][4] = {};
  for (int kt = 0; kt < K_DIM / 64; ++kt) {
    __syncthreads();
    int ar = tid >> 1;
    int ac = (tid & 1) * 32;
    const float* xp = Xf + (size_t)(r0 + ar) * K_DIM + kt * 64 + ac;
#pragma unroll
    for (int jj = 0; jj < 8; ++jj) {
      f32x4 v = *(const f32x4*)(xp + jj * 4);
      As[ar][ac + jj * 4 + 0] = f32_to_bf16(v[0]);
      As[ar][ac + jj * 4 + 1] = f32_to_bf16(v[1]);
      As[ar][ac + jj * 4 + 2] = f32_to_bf16(v[2]);
      As[ar][ac + jj * 4 + 3] = f32_to_bf16(v[3]);
    }
    int bk_ = tid >> 2;
    int bc = (tid & 3) * 32;
    const float* wp = Wf + (size_t)(kt * 64 + bk_) * N_DIM + c0 + bc;
#pragma unroll
    for (int jj = 0; jj < 8; ++jj) {
      f32x4 v = *(const f32x4*)(wp + jj * 4);
      Bs[bc + jj * 4 + 0][bk_] = f32_to_bf16(v[0]);
      Bs[bc + jj * 4 + 1][bk_] = f32_to_bf16(v[1]);
      Bs[bc + jj * 4 + 2][bk_] = f32_to_bf16(v[2]);
      Bs[bc + jj * 4 + 3][bk_] = f32_to_bf16(v[3]);
    }
    __syncthreads();
#pragma unroll
    for (int ks = 0; ks < 2; ++ks) {
      int co = ks * 32 + (lane >> 4) * 8;
      int rA = wr * 64 + (lane & 15);
      int rB = wc * 64 + (lane & 15);
      short8 a[4], b[4];
#pragma unroll
      for (int m = 0; m < 4; ++m) a[m] = *(const short8*)&As[rA + m * 16][co];
#pragma unroll
      for (int n = 0; n < 4; ++n) b[n] = *(const short8*)&Bs[rB + n * 16][co];
#pragma unroll
      for (int m = 0; m < 4; ++m)
#pragma unroll
        for (int n = 0; n < 4; ++n)
          acc[m][n] = __builtin_amdgcn_mfma_f32_16x16x32_bf16(a[m], b[n], acc[m][n], 0, 0, 0);
    }
  }
  const float S = 65536.0f, IS = 1.0f / 65536.0f;
  int lr = (lane >> 4) * 4;
  int lc = lane & 15;
#pragma unroll
  for (int n = 0; n < 4; ++n) {
    int gcol = c0 + wc * 64 + n * 16 + lc;
    float bq = rintf(bias[gcol] * S) * IS;
#pragma unroll
    for (int m = 0; m < 4; ++m) {
      int grow = r0 + wr * 64 + m * 16 + lr;
      float* outp = C + (size_t)grow * N_DIM + gcol;
#pragma unroll
      for (int r = 0; r < 4; ++r) {
        float t = rintf(acc[m][n][r] * S) * IS + bq;
        t = t > 0.0f ? t : 0.0f;
        outp[(size_t)r * N_DIM] = t;
      }
    }
  }
}

extern "C" void kernel_launch(void* const* d_in, const int* in_sizes, int n_in,
                              void* d_out, int out_size, void* d_ws, size_t ws_size,
                              hipStream_t stream) {
  const float* x = (const float*)d_in[0];
  const float* w = (const float*)d_in[1];
  const float* b = (const float*)d_in[2];
  float* out = (float*)d_out;

  size_t needA = (size_t)M_DIM * K_DIM * sizeof(unsigned short);
  size_t needB = (size_t)K_DIM * N_DIM * sizeof(unsigned short);

  if (ws_size >= needA + needB) {
    unsigned short* Abf = (unsigned short*)d_ws;
    unsigned short* Btbf = (unsigned short*)((char*)d_ws + needA);
    cvt_x_kernel<<<(M_DIM * (size_t)K_DIM / 8 + 255) / 256, 256, 0, stream>>>(x, Abf);
    transpose_cvt_w_kernel<<<dim3(N_DIM / 64, K_DIM / 64), 256, 0, stream>>>(w, Btbf);
    gemm8_kernel<<<256, 512, 0, stream>>>(Abf, Btbf, b, out);
  } else {
    gemm_fb_kernel<<<dim3(N_DIM / 128, M_DIM / 128), 256, 0, stream>>>(x, w, b, out);
  }
}